// Round 15
// baseline (262.954 us; speedup 1.0000x reference)
//
#include <hip/hip_runtime.h>
#include <math.h>

#define HD 64
#define KVBLK 64
#define LP 72

typedef __attribute__((ext_vector_type(8))) short short8;
typedef __attribute__((ext_vector_type(4))) short short4v;
typedef __attribute__((ext_vector_type(4))) float f32x4;

__device__ __forceinline__ short f2bf(float f) {
    union { float f; unsigned u; } in;
    in.f = f;
    unsigned r = (in.u + 0x7fff + ((in.u >> 16) & 1)) >> 16;  // RNE
    return (short)r;
}

// ---------------- fp32 -> bf16 convert ----------------
__global__ __launch_bounds__(256) void convert_bf16(const float* __restrict__ in,
                                                    short* __restrict__ out, long n4) {
    long i = blockIdx.x * 256L + threadIdx.x;
    if (i >= n4) return;
    float4 v = reinterpret_cast<const float4*>(in)[i];
    short4v o;
    o[0] = f2bf(v.x); o[1] = f2bf(v.y); o[2] = f2bf(v.z); o[3] = f2bf(v.w);
    reinterpret_cast<short4v*>(out)[i] = o;
}

// ------------- transpose + convert: [K][N] fp32 -> [N][K] bf16 -------------
__global__ __launch_bounds__(256) void transpose_bf16(const float* __restrict__ in,
                                                      short* __restrict__ out, int K, int N) {
    __shared__ float tile[32][33];
    const int n0 = blockIdx.x * 32, k0 = blockIdx.y * 32;
    const int tx = threadIdx.x & 31, ty = threadIdx.x >> 5;
    #pragma unroll
    for (int i = ty; i < 32; i += 8)
        tile[i][tx] = in[(size_t)(k0 + i) * N + n0 + tx];
    __syncthreads();
    #pragma unroll
    for (int i = ty; i < 32; i += 8)
        out[(size_t)(n0 + i) * K + k0 + tx] = f2bf(tile[tx][i]);
}

// ------- bf16 MFMA GEMM: 256x128 tile, 8x4 wave blocking, BK=32, 2-buf -------
// WVT: V-columns (col>=1536, block-uniform) scatter to vT[(b*12+h)*64+d][key640]
// instead of C (fuses transpose_v; qkvb V region never written/read).
template <typename OutT, bool WVT>
__global__ __launch_bounds__(256, 2) void gemm_bf16(const short* __restrict__ A,
                                                    const short* __restrict__ Bt,
                                                    const float* __restrict__ bias,
                                                    OutT* __restrict__ C,
                                                    short* __restrict__ vT,
                                                    int M, int N, int K, int nbn) {
    __shared__ short As[2][128 * 64];   // 256 rows packed in pairs
    __shared__ short Bs[2][64 * 64];    // 128 rows packed in pairs
    const int tid = threadIdx.x;
    const int w = tid >> 6, lane = tid & 63;
    const int g = lane >> 4, l16 = lane & 15;

    const int nwg = gridDim.x;
    const int q = nwg >> 3, r = nwg & 7;
    const int xcd = blockIdx.x & 7, loc = blockIdx.x >> 3;
    const int wgid = (xcd < r ? xcd * (q + 1) : r * (q + 1) + (xcd - r) * q) + loc;
    const int bm = wgid / nbn, bn = wgid % nbn;
    const int m0 = bm * 256, n0 = bn * 128;
    const int wm = (w >> 1) * 128, wn = (w & 1) * 64;

    f32x4 acc[8][4] = {};
    const int NT = K >> 5;   // BK=32

    auto stage = [&](int buf, int k0) {
        #pragma unroll
        for (int j = 0; j < 4; ++j) {
            const int o = j * 4096 + tid * 16;
            const int R = o >> 7;
            const int sl = ((o >> 4) & 7) ^ (R & 7);
            const int rr = 2 * R + (sl >> 2);
            const int cblk = sl & 3;
            long arow = m0 + rr; if (arow > M - 1) arow = M - 1;
            const short* ga = A + arow * K + k0 + cblk * 8;
            __builtin_amdgcn_global_load_lds(
                (const __attribute__((address_space(1))) unsigned*)ga,
                (__attribute__((address_space(3))) unsigned*)((char*)&As[buf][0] + o),
                16, 0, 0);
        }
        #pragma unroll
        for (int j = 0; j < 2; ++j) {
            const int o = j * 4096 + tid * 16;
            const int R = o >> 7;
            const int sl = ((o >> 4) & 7) ^ (R & 7);
            const int rr = 2 * R + (sl >> 2);
            const int cblk = sl & 3;
            const short* gb = Bt + (size_t)(n0 + rr) * K + k0 + cblk * 8;
            __builtin_amdgcn_global_load_lds(
                (const __attribute__((address_space(1))) unsigned*)gb,
                (__attribute__((address_space(3))) unsigned*)((char*)&Bs[buf][0] + o),
                16, 0, 0);
        }
    };

    stage(0, 0);
    __syncthreads();

    for (int kt = 0; kt < NT; ++kt) {
        const int cur = kt & 1;
        if (kt + 1 < NT) stage(cur ^ 1, (kt + 1) * 32);

        short8 af[8], bfr[4];
        #pragma unroll
        for (int mi = 0; mi < 8; ++mi) {
            const int ra = wm + mi * 16 + l16;
            const int Ra = ra >> 1;
            const int sla = (4 * (ra & 1) + g) ^ (Ra & 7);
            af[mi] = *reinterpret_cast<const short8*>(&As[cur][Ra * 64 + sla * 8]);
        }
        #pragma unroll
        for (int ni = 0; ni < 4; ++ni) {
            const int rb = wn + ni * 16 + l16;
            const int Rb = rb >> 1;
            const int slb = (4 * (rb & 1) + g) ^ (Rb & 7);
            bfr[ni] = *reinterpret_cast<const short8*>(&Bs[cur][Rb * 64 + slb * 8]);
        }
        __builtin_amdgcn_s_setprio(1);
        #pragma unroll
        for (int mi = 0; mi < 8; ++mi)
            #pragma unroll
            for (int ni = 0; ni < 4; ++ni)
                acc[mi][ni] = __builtin_amdgcn_mfma_f32_16x16x32_bf16(
                    af[mi], bfr[ni], acc[mi][ni], 0, 0, 0);
        __builtin_amdgcn_s_setprio(0);
        __syncthreads();
    }

    float bv[4];
    #pragma unroll
    for (int ni = 0; ni < 4; ++ni) bv[ni] = bias[n0 + wn + ni * 16 + l16];
    #pragma unroll
    for (int mi = 0; mi < 8; ++mi) {
        #pragma unroll
        for (int rr = 0; rr < 4; ++rr) {
            const int row = m0 + wm + mi * 16 + g * 4 + rr;
            if (row < M) {
                if (WVT && n0 >= 1536) {
                    // V panel: scatter to vT (fused transpose_v)
                    const int bb = row / 577, key = row - bb * 577;
                    #pragma unroll
                    for (int ni = 0; ni < 4; ++ni) {
                        const int vcol = n0 + wn + ni * 16 + l16 - 1536;
                        vT[(size_t)(bb * 768 + vcol) * 640 + key] =
                            f2bf(acc[mi][ni][rr] + bv[ni]);
                    }
                } else {
                    #pragma unroll
                    for (int ni = 0; ni < 4; ++ni) {
                        float val = acc[mi][ni][rr] + bv[ni];
                        if constexpr (__is_same(OutT, float))
                            C[(size_t)row * N + n0 + wn + ni * 16 + l16] = val;
                        else
                            C[(size_t)row * N + n0 + wn + ni * 16 + l16] = f2bf(val);
                    }
                }
            }
        }
    }
}

// ------- flash attention: QBLK=128 (2 q-groups/wave), swapped-QK^T -------
__global__ __launch_bounds__(256) void flash_attn(const short* __restrict__ qkvb,
                                                  const short* __restrict__ vT,
                                                  const float* __restrict__ scale,
                                                  short* __restrict__ out) {
    constexpr int Nn = 577, Cc = 768, C3 = 2304, NQB = 5, NH = 12, NT = 10, NKP = 640;
    const int bid = blockIdx.x;
    const int swz = (bid & 7) * 240 + (bid >> 3);   // 1920 blocks, 240 per XCD
    const int q0 = (swz % NQB) * 128;
    const int h  = (swz / NQB) % NH;
    const int b  = swz / (NQB * NH);
    const int qb2 = q0 >> 6;   // diag tiles: qb2 (u=0), qb2+1 (u=1)

    const int tid  = threadIdx.x;
    const int w    = tid >> 6;
    const int lane = tid & 63;
    const int g    = lane >> 4;
    const int l16  = lane & 15;

    __shared__ alignas(16) short Ks[2][KVBLK * HD];
    __shared__ alignas(16) short Vts[2][HD * KVBLK];
    __shared__ alignas(16) short Ps[4][2][16][LP];

    const float sl2 = scale[h] * 1.44269504088896f;
    const float thr = 8.0f / sl2;
    const short* base = qkvb + (size_t)b * Nn * C3;
    const short* kglob = base + Cc + h * HD;
    const short* vtb = vT + (size_t)(b * NH + h) * HD * NKP;

    short8 aq[2][2];
    #pragma unroll
    for (int u = 0; u < 2; ++u) {
        const int qrow = q0 + u * 64 + w * 16 + l16;
        const int qr = qrow < Nn ? qrow : Nn - 1;
        const short* qp = base + (size_t)qr * C3 + h * HD;
        aq[u][0] = *reinterpret_cast<const short8*>(qp + 8 * g);
        aq[u][1] = *reinterpret_cast<const short8*>(qp + 32 + 8 * g);
    }

    f32x4 oacc[2][4] = {};
    float mrun[2] = {-INFINITY, -INFINITY}, m2[2] = {-INFINITY, -INFINITY},
          lrun[2] = {0.f, 0.f};

    const int kst_row = lane >> 3;
    const int kst_dblk = (lane & 7) ^ (lane >> 3);

    auto stageK = [&](int bufi, int kv0) {
        #pragma unroll
        for (int t = 0; t < 2; ++t) {
            const int i = 2 * w + t;
            int kr = kv0 + 8 * i + kst_row;
            if (kr > Nn - 1) kr = Nn - 1;
            const short* src = kglob + (size_t)kr * C3 + kst_dblk * 8;
            __builtin_amdgcn_global_load_lds(
                (const __attribute__((address_space(1))) unsigned*)src,
                (__attribute__((address_space(3))) unsigned*)&Ks[bufi][i * 512],
                16, 0, 0);
        }
    };
    auto stageV = [&](int bufi, int kv0) {
        #pragma unroll
        for (int t = 0; t < 2; ++t) {
            const int i = 2 * w + t;
            const int r = 8 * i + kst_row;
            const int kb = (lane & 7) ^ (r & 7);
            const short* src = vtb + (size_t)r * NKP + kv0 + kb * 8;
            __builtin_amdgcn_global_load_lds(
                (const __attribute__((address_space(1))) unsigned*)src,
                (__attribute__((address_space(3))) unsigned*)&Vts[bufi][i * 512],
                16, 0, 0);
        }
    };

    stageK(0, 0);
    stageV(0, 0);
    __syncthreads();

    for (int t = 0; t < NT; ++t) {
        const int cur = t & 1, nxt = cur ^ 1;
        const int kv0 = t * KVBLK;
        const bool more = (t + 1 < NT);
        if (more) { stageK(nxt, kv0 + KVBLK); stageV(nxt, kv0 + KVBLK); }

        // ---- S^T for both q-groups ----
        f32x4 sacc[2][4] = {};
        __builtin_amdgcn_s_setprio(1);
        #pragma unroll
        for (int u = 0; u < 2; ++u)
            #pragma unroll
            for (int f = 0; f < 4; ++f)
                #pragma unroll
                for (int c = 0; c < 2; ++c) {
                    const int slot = (4 * c + g) ^ (l16 & 7);
                    short8 ak = *reinterpret_cast<const short8*>(
                        &Ks[cur][(16 * f + l16) * 64 + slot * 8]);
                    sacc[u][f] = __builtin_amdgcn_mfma_f32_16x16x32_bf16(
                        ak, aq[u][c], sacc[u][f], 0, 0, 0);
                }
        __builtin_amdgcn_s_setprio(0);

        // ---- softmax + P-store per group ----
        #pragma unroll
        for (int u = 0; u < 2; ++u) {
            const int ig = q0 + u * 64 + w * 16 + l16;
            float s2[4][4];
            #pragma unroll
            for (int f = 0; f < 4; ++f)
                #pragma unroll
                for (int r = 0; r < 4; ++r)
                    s2[f][r] = sacc[u][f][r];
            if (t == qb2 + u || t == NT - 1) {
                #pragma unroll
                for (int f = 0; f < 4; ++f)
                    #pragma unroll
                    for (int r = 0; r < 4; ++r) {
                        const int jg = kv0 + 16 * f + 4 * g + r;
                        if (jg >= Nn || (jg == ig && ig >= 1)) s2[f][r] = -INFINITY;
                    }
            }

            float mx = s2[0][0];
            #pragma unroll
            for (int f = 0; f < 4; ++f)
                #pragma unroll
                for (int r = 0; r < 4; ++r)
                    if (f + r) mx = fmaxf(mx, s2[f][r]);
            mx = fmaxf(mx, __shfl_xor(mx, 16, 64));
            mx = fmaxf(mx, __shfl_xor(mx, 32, 64));

            if (__any(mx > mrun[u] + thr)) {
                const float mnew = fmaxf(mrun[u], mx);
                const float m2new = mnew * sl2;
                const float fac = __builtin_amdgcn_exp2f(m2[u] - m2new);
                mrun[u] = mnew; m2[u] = m2new;
                lrun[u] *= fac;
                #pragma unroll
                for (int r = 0; r < 4; ++r) {
                    const float fr = __shfl(fac, 16 * g + 4 * g + r, 64);
                    #pragma unroll
                    for (int df = 0; df < 4; ++df) oacc[u][df][r] *= fr;
                }
            }

            float sum = 0.f;
            #pragma unroll
            for (int f = 0; f < 4; ++f)
                #pragma unroll
                for (int r = 0; r < 4; ++r) {
                    float p = __builtin_amdgcn_exp2f(fmaf(s2[f][r], sl2, -m2[u]));
                    s2[f][r] = p;
                    sum += p;
                }
            sum += __shfl_xor(sum, 16, 64);
            sum += __shfl_xor(sum, 32, 64);
            lrun[u] += sum;

            #pragma unroll
            for (int f = 0; f < 4; ++f) {
                unsigned plo, phi;
                asm("v_cvt_pk_bf16_f32 %0, %1, %2" : "=v"(plo) : "v"(s2[f][0]), "v"(s2[f][1]));
                asm("v_cvt_pk_bf16_f32 %0, %1, %2" : "=v"(phi) : "v"(s2[f][2]), "v"(s2[f][3]));
                unsigned* dst = reinterpret_cast<unsigned*>(&Ps[w][u][l16][16 * f + 4 * g]);
                dst[0] = plo; dst[1] = phi;
            }
        }
        asm volatile("s_waitcnt lgkmcnt(0)" ::: "memory");

        // ---- O += P @ V for both groups ----
        __builtin_amdgcn_s_setprio(1);
        #pragma unroll
        for (int u = 0; u < 2; ++u)
            #pragma unroll
            for (int c = 0; c < 2; ++c) {
                short8 pa = *reinterpret_cast<const short8*>(&Ps[w][u][l16][32 * c + 8 * g]);
                #pragma unroll
                for (int df = 0; df < 4; ++df) {
                    const int slot = (4 * c + g) ^ (l16 & 7);
                    short8 bv = *reinterpret_cast<const short8*>(
                        &Vts[cur][(16 * df + l16) * 64 + slot * 8]);
                    oacc[u][df] = __builtin_amdgcn_mfma_f32_16x16x32_bf16(
                        pa, bv, oacc[u][df], 0, 0, 0);
                }
            }
        __builtin_amdgcn_s_setprio(0);
        __syncthreads();
    }

    #pragma unroll
    for (int u = 0; u < 2; ++u)
        #pragma unroll
        for (int r = 0; r < 4; ++r) {
            const int og = q0 + u * 64 + w * 16 + g * 4 + r;
            if (og < Nn) {
                const float lr_r = __shfl(lrun[u], 16 * g + 4 * g + r, 64);
                const float inv = 1.f / lr_r;
                #pragma unroll
                for (int df = 0; df < 4; ++df)
                    out[(size_t)(b * Nn + og) * Cc + h * HD + 16 * df + l16] =
                        f2bf(oacc[u][df][r] * inv);
            }
        }
}

extern "C" void kernel_launch(void* const* d_in, const int* in_sizes, int n_in,
                              void* d_out, int out_size, void* d_ws, size_t ws_size,
                              hipStream_t stream) {
    const float* x      = (const float*)d_in[0];
    const float* w_qkv  = (const float*)d_in[1];
    const float* b_qkv  = (const float*)d_in[2];
    const float* scale  = (const float*)d_in[3];
    const float* w_proj = (const float*)d_in[4];
    const float* b_proj = (const float*)d_in[5];
    float* out = (float*)d_out;

    const int B = 32, N = 577, C = 768, H = 12;
    const int M  = B * N;     // 18464
    const int C3 = 3 * C;     // 2304
    const int MB2 = (M + 255) / 256;   // 73

    short* qkvb   = (short*)d_ws;
    short* attn_o = qkvb + (size_t)M * C3;
    short* xb     = attn_o + (size_t)M * C;
    short* wqkvT  = xb + (size_t)M * C;
    short* wprojT = wqkvT + (size_t)C3 * C;
    short* vT     = wprojT + (size_t)C * C;   // B*H x 64 x 640

    dim3 blk(256);
    const long n4 = (long)M * C / 4;
    convert_bf16<<<dim3((n4 + 255) / 256), blk, 0, stream>>>(x, xb, n4);
    transpose_bf16<<<dim3(C3 / 32, C / 32), blk, 0, stream>>>(w_qkv, wqkvT, C, C3);
    transpose_bf16<<<dim3(C / 32, C / 32), blk, 0, stream>>>(w_proj, wprojT, C, C);

    gemm_bf16<short, true><<<dim3(MB2 * (C3 / 128)), blk, 0, stream>>>(
        xb, wqkvT, b_qkv, qkvb, vT, M, C3, C, C3 / 128);

    flash_attn<<<dim3(((N + 127) / 128) * H * B), blk, 0, stream>>>(qkvb, vT, scale, attn_o);

    gemm_bf16<float, false><<<dim3(MB2 * (C / 128)), blk, 0, stream>>>(
        attn_o, wprojT, b_proj, out, nullptr, M, C, C, C / 128);
}

// Round 16
// 246.995 us; speedup vs baseline: 1.0646x; 1.0646x over previous
//
#include <hip/hip_runtime.h>
#include <math.h>

#define HD 64
#define KVBLK 64
#define LP 72

typedef __attribute__((ext_vector_type(8))) short short8;
typedef __attribute__((ext_vector_type(4))) short short4v;
typedef __attribute__((ext_vector_type(4))) float f32x4;

__device__ __forceinline__ short f2bf(float f) {
    union { float f; unsigned u; } in;
    in.f = f;
    unsigned r = (in.u + 0x7fff + ((in.u >> 16) & 1)) >> 16;  // RNE
    return (short)r;
}

// ---------------- fp32 -> bf16 convert ----------------
__global__ __launch_bounds__(256) void convert_bf16(const float* __restrict__ in,
                                                    short* __restrict__ out, long n4) {
    long i = blockIdx.x * 256L + threadIdx.x;
    if (i >= n4) return;
    float4 v = reinterpret_cast<const float4*>(in)[i];
    short4v o;
    o[0] = f2bf(v.x); o[1] = f2bf(v.y); o[2] = f2bf(v.z); o[3] = f2bf(v.w);
    reinterpret_cast<short4v*>(out)[i] = o;
}

// ------------- transpose + convert: [K][N] fp32 -> [N][K] bf16 -------------
__global__ __launch_bounds__(256) void transpose_bf16(const float* __restrict__ in,
                                                      short* __restrict__ out, int K, int N) {
    __shared__ float tile[32][33];
    const int n0 = blockIdx.x * 32, k0 = blockIdx.y * 32;
    const int tx = threadIdx.x & 31, ty = threadIdx.x >> 5;
    #pragma unroll
    for (int i = ty; i < 32; i += 8)
        tile[i][tx] = in[(size_t)(k0 + i) * N + n0 + tx];
    __syncthreads();
    #pragma unroll
    for (int i = ty; i < 32; i += 8)
        out[(size_t)(n0 + i) * K + k0 + tx] = f2bf(tile[tx][i]);
}

// ------- V pre-transpose: qkv V-part [b][key][h][d] -> vT[(b*H+h)][d][key640] -------
__global__ __launch_bounds__(256) void transpose_v(const short* __restrict__ qkvb,
                                                   short* __restrict__ vT) {
    constexpr int Nn = 577, C3 = 2304, NH = 12, NKP = 640;
    const int bh = blockIdx.x;
    const int kt = blockIdx.y;
    const int b = bh / NH, h = bh % NH;
    const int tid = threadIdx.x;
    __shared__ short tile[64][33];

    const int tk = tid >> 3;
    const int key = kt * 32 + tk;
    const int d0 = (tid & 7) * 8;
    short8 v = {0, 0, 0, 0, 0, 0, 0, 0};
    if (key < Nn)
        v = *reinterpret_cast<const short8*>(
            qkvb + (size_t)(b * Nn + key) * C3 + 1536 + h * 64 + d0);
    #pragma unroll
    for (int i = 0; i < 8; ++i) tile[d0 + i][tk] = v[i];
    __syncthreads();

    const int d = tid >> 2;
    const int kb = (tid & 3) * 8;
    short8 o;
    #pragma unroll
    for (int i = 0; i < 8; ++i) o[i] = tile[d][kb + i];
    *reinterpret_cast<short8*>(vT + (size_t)(bh * 64 + d) * NKP + kt * 32 + kb) = o;
}

// ------- bf16 MFMA GEMM: 256x128 tile, 8x4 wave blocking, BK=32, 2-buf (r14) -------
template <typename OutT>
__global__ __launch_bounds__(256, 2) void gemm_bf16(const short* __restrict__ A,
                                                    const short* __restrict__ Bt,
                                                    const float* __restrict__ bias,
                                                    OutT* __restrict__ C,
                                                    int M, int N, int K, int nbn) {
    __shared__ short As[2][128 * 64];   // 256 rows packed in pairs
    __shared__ short Bs[2][64 * 64];    // 128 rows packed in pairs
    const int tid = threadIdx.x;
    const int w = tid >> 6, lane = tid & 63;
    const int g = lane >> 4, l16 = lane & 15;

    const int nwg = gridDim.x;
    const int q = nwg >> 3, r = nwg & 7;
    const int xcd = blockIdx.x & 7, loc = blockIdx.x >> 3;
    const int wgid = (xcd < r ? xcd * (q + 1) : r * (q + 1) + (xcd - r) * q) + loc;
    const int bm = wgid / nbn, bn = wgid % nbn;
    const int m0 = bm * 256, n0 = bn * 128;
    const int wm = (w >> 1) * 128, wn = (w & 1) * 64;

    f32x4 acc[8][4] = {};
    const int NT = K >> 5;   // BK=32

    auto stage = [&](int buf, int k0) {
        #pragma unroll
        for (int j = 0; j < 4; ++j) {
            const int o = j * 4096 + tid * 16;
            const int R = o >> 7;
            const int sl = ((o >> 4) & 7) ^ (R & 7);
            const int rr = 2 * R + (sl >> 2);
            const int cblk = sl & 3;
            long arow = m0 + rr; if (arow > M - 1) arow = M - 1;
            const short* ga = A + arow * K + k0 + cblk * 8;
            __builtin_amdgcn_global_load_lds(
                (const __attribute__((address_space(1))) unsigned*)ga,
                (__attribute__((address_space(3))) unsigned*)((char*)&As[buf][0] + o),
                16, 0, 0);
        }
        #pragma unroll
        for (int j = 0; j < 2; ++j) {
            const int o = j * 4096 + tid * 16;
            const int R = o >> 7;
            const int sl = ((o >> 4) & 7) ^ (R & 7);
            const int rr = 2 * R + (sl >> 2);
            const int cblk = sl & 3;
            const short* gb = Bt + (size_t)(n0 + rr) * K + k0 + cblk * 8;
            __builtin_amdgcn_global_load_lds(
                (const __attribute__((address_space(1))) unsigned*)gb,
                (__attribute__((address_space(3))) unsigned*)((char*)&Bs[buf][0] + o),
                16, 0, 0);
        }
    };

    stage(0, 0);
    __syncthreads();

    for (int kt = 0; kt < NT; ++kt) {
        const int cur = kt & 1;
        if (kt + 1 < NT) stage(cur ^ 1, (kt + 1) * 32);

        short8 af[8], bfr[4];
        #pragma unroll
        for (int mi = 0; mi < 8; ++mi) {
            const int ra = wm + mi * 16 + l16;
            const int Ra = ra >> 1;
            const int sla = (4 * (ra & 1) + g) ^ (Ra & 7);
            af[mi] = *reinterpret_cast<const short8*>(&As[cur][Ra * 64 + sla * 8]);
        }
        #pragma unroll
        for (int ni = 0; ni < 4; ++ni) {
            const int rb = wn + ni * 16 + l16;
            const int Rb = rb >> 1;
            const int slb = (4 * (rb & 1) + g) ^ (Rb & 7);
            bfr[ni] = *reinterpret_cast<const short8*>(&Bs[cur][Rb * 64 + slb * 8]);
        }
        __builtin_amdgcn_s_setprio(1);
        #pragma unroll
        for (int mi = 0; mi < 8; ++mi)
            #pragma unroll
            for (int ni = 0; ni < 4; ++ni)
                acc[mi][ni] = __builtin_amdgcn_mfma_f32_16x16x32_bf16(
                    af[mi], bfr[ni], acc[mi][ni], 0, 0, 0);
        __builtin_amdgcn_s_setprio(0);
        __syncthreads();
    }

    float bv[4];
    #pragma unroll
    for (int ni = 0; ni < 4; ++ni) bv[ni] = bias[n0 + wn + ni * 16 + l16];
    #pragma unroll
    for (int mi = 0; mi < 8; ++mi) {
        #pragma unroll
        for (int rr = 0; rr < 4; ++rr) {
            const int row = m0 + wm + mi * 16 + g * 4 + rr;
            if (row < M) {
                #pragma unroll
                for (int ni = 0; ni < 4; ++ni) {
                    float val = acc[mi][ni][rr] + bv[ni];
                    if constexpr (__is_same(OutT, float))
                        C[(size_t)row * N + n0 + wn + ni * 16 + l16] = val;
                    else
                        C[(size_t)row * N + n0 + wn + ni * 16 + l16] = f2bf(val);
                }
            }
        }
    }
}

// ------- flash attention: QBLK=128 (2 q-groups/wave), swapped-QK^T (r15, kept) -------
__global__ __launch_bounds__(256) void flash_attn(const short* __restrict__ qkvb,
                                                  const short* __restrict__ vT,
                                                  const float* __restrict__ scale,
                                                  short* __restrict__ out) {
    constexpr int Nn = 577, Cc = 768, C3 = 2304, NQB = 5, NH = 12, NT = 10, NKP = 640;
    const int bid = blockIdx.x;
    const int swz = (bid & 7) * 240 + (bid >> 3);   // 1920 blocks, 240 per XCD
    const int q0 = (swz % NQB) * 128;
    const int h  = (swz / NQB) % NH;
    const int b  = swz / (NQB * NH);
    const int qb2 = q0 >> 6;

    const int tid  = threadIdx.x;
    const int w    = tid >> 6;
    const int lane = tid & 63;
    const int g    = lane >> 4;
    const int l16  = lane & 15;

    __shared__ alignas(16) short Ks[2][KVBLK * HD];
    __shared__ alignas(16) short Vts[2][HD * KVBLK];
    __shared__ alignas(16) short Ps[4][2][16][LP];

    const float sl2 = scale[h] * 1.44269504088896f;
    const float thr = 8.0f / sl2;
    const short* base = qkvb + (size_t)b * Nn * C3;
    const short* kglob = base + Cc + h * HD;
    const short* vtb = vT + (size_t)(b * NH + h) * HD * NKP;

    short8 aq[2][2];
    #pragma unroll
    for (int u = 0; u < 2; ++u) {
        const int qrow = q0 + u * 64 + w * 16 + l16;
        const int qr = qrow < Nn ? qrow : Nn - 1;
        const short* qp = base + (size_t)qr * C3 + h * HD;
        aq[u][0] = *reinterpret_cast<const short8*>(qp + 8 * g);
        aq[u][1] = *reinterpret_cast<const short8*>(qp + 32 + 8 * g);
    }

    f32x4 oacc[2][4] = {};
    float mrun[2] = {-INFINITY, -INFINITY}, m2[2] = {-INFINITY, -INFINITY},
          lrun[2] = {0.f, 0.f};

    const int kst_row = lane >> 3;
    const int kst_dblk = (lane & 7) ^ (lane >> 3);

    auto stageK = [&](int bufi, int kv0) {
        #pragma unroll
        for (int t = 0; t < 2; ++t) {
            const int i = 2 * w + t;
            int kr = kv0 + 8 * i + kst_row;
            if (kr > Nn - 1) kr = Nn - 1;
            const short* src = kglob + (size_t)kr * C3 + kst_dblk * 8;
            __builtin_amdgcn_global_load_lds(
                (const __attribute__((address_space(1))) unsigned*)src,
                (__attribute__((address_space(3))) unsigned*)&Ks[bufi][i * 512],
                16, 0, 0);
        }
    };
    auto stageV = [&](int bufi, int kv0) {
        #pragma unroll
        for (int t = 0; t < 2; ++t) {
            const int i = 2 * w + t;
            const int r = 8 * i + kst_row;
            const int kb = (lane & 7) ^ (r & 7);
            const short* src = vtb + (size_t)r * NKP + kv0 + kb * 8;
            __builtin_amdgcn_global_load_lds(
                (const __attribute__((address_space(1))) unsigned*)src,
                (__attribute__((address_space(3))) unsigned*)&Vts[bufi][i * 512],
                16, 0, 0);
        }
    };

    stageK(0, 0);
    stageV(0, 0);
    __syncthreads();

    for (int t = 0; t < NT; ++t) {
        const int cur = t & 1, nxt = cur ^ 1;
        const int kv0 = t * KVBLK;
        const bool more = (t + 1 < NT);
        if (more) { stageK(nxt, kv0 + KVBLK); stageV(nxt, kv0 + KVBLK); }

        f32x4 sacc[2][4] = {};
        __builtin_amdgcn_s_setprio(1);
        #pragma unroll
        for (int u = 0; u < 2; ++u)
            #pragma unroll
            for (int f = 0; f < 4; ++f)
                #pragma unroll
                for (int c = 0; c < 2; ++c) {
                    const int slot = (4 * c + g) ^ (l16 & 7);
                    short8 ak = *reinterpret_cast<const short8*>(
                        &Ks[cur][(16 * f + l16) * 64 + slot * 8]);
                    sacc[u][f] = __builtin_amdgcn_mfma_f32_16x16x32_bf16(
                        ak, aq[u][c], sacc[u][f], 0, 0, 0);
                }
        __builtin_amdgcn_s_setprio(0);

        #pragma unroll
        for (int u = 0; u < 2; ++u) {
            const int ig = q0 + u * 64 + w * 16 + l16;
            float s2[4][4];
            #pragma unroll
            for (int f = 0; f < 4; ++f)
                #pragma unroll
                for (int r = 0; r < 4; ++r)
                    s2[f][r] = sacc[u][f][r];
            if (t == qb2 + u || t == NT - 1) {
                #pragma unroll
                for (int f = 0; f < 4; ++f)
                    #pragma unroll
                    for (int r = 0; r < 4; ++r) {
                        const int jg = kv0 + 16 * f + 4 * g + r;
                        if (jg >= Nn || (jg == ig && ig >= 1)) s2[f][r] = -INFINITY;
                    }
            }

            float mx = s2[0][0];
            #pragma unroll
            for (int f = 0; f < 4; ++f)
                #pragma unroll
                for (int r = 0; r < 4; ++r)
                    if (f + r) mx = fmaxf(mx, s2[f][r]);
            mx = fmaxf(mx, __shfl_xor(mx, 16, 64));
            mx = fmaxf(mx, __shfl_xor(mx, 32, 64));

            if (__any(mx > mrun[u] + thr)) {
                const float mnew = fmaxf(mrun[u], mx);
                const float m2new = mnew * sl2;
                const float fac = __builtin_amdgcn_exp2f(m2[u] - m2new);
                mrun[u] = mnew; m2[u] = m2new;
                lrun[u] *= fac;
                #pragma unroll
                for (int r = 0; r < 4; ++r) {
                    const float fr = __shfl(fac, 16 * g + 4 * g + r, 64);
                    #pragma unroll
                    for (int df = 0; df < 4; ++df) oacc[u][df][r] *= fr;
                }
            }

            float sum = 0.f;
            #pragma unroll
            for (int f = 0; f < 4; ++f)
                #pragma unroll
                for (int r = 0; r < 4; ++r) {
                    float p = __builtin_amdgcn_exp2f(fmaf(s2[f][r], sl2, -m2[u]));
                    s2[f][r] = p;
                    sum += p;
                }
            sum += __shfl_xor(sum, 16, 64);
            sum += __shfl_xor(sum, 32, 64);
            lrun[u] += sum;

            #pragma unroll
            for (int f = 0; f < 4; ++f) {
                unsigned plo, phi;
                asm("v_cvt_pk_bf16_f32 %0, %1, %2" : "=v"(plo) : "v"(s2[f][0]), "v"(s2[f][1]));
                asm("v_cvt_pk_bf16_f32 %0, %1, %2" : "=v"(phi) : "v"(s2[f][2]), "v"(s2[f][3]));
                unsigned* dst = reinterpret_cast<unsigned*>(&Ps[w][u][l16][16 * f + 4 * g]);
                dst[0] = plo; dst[1] = phi;
            }
        }
        asm volatile("s_waitcnt lgkmcnt(0)" ::: "memory");

        __builtin_amdgcn_s_setprio(1);
        #pragma unroll
        for (int u = 0; u < 2; ++u)
            #pragma unroll
            for (int c = 0; c < 2; ++c) {
                short8 pa = *reinterpret_cast<const short8*>(&Ps[w][u][l16][32 * c + 8 * g]);
                #pragma unroll
                for (int df = 0; df < 4; ++df) {
                    const int slot = (4 * c + g) ^ (l16 & 7);
                    short8 bv = *reinterpret_cast<const short8*>(
                        &Vts[cur][(16 * df + l16) * 64 + slot * 8]);
                    oacc[u][df] = __builtin_amdgcn_mfma_f32_16x16x32_bf16(
                        pa, bv, oacc[u][df], 0, 0, 0);
                }
            }
        __builtin_amdgcn_s_setprio(0);
        __syncthreads();
    }

    #pragma unroll
    for (int u = 0; u < 2; ++u)
        #pragma unroll
        for (int r = 0; r < 4; ++r) {
            const int og = q0 + u * 64 + w * 16 + g * 4 + r;
            if (og < Nn) {
                const float lr_r = __shfl(lrun[u], 16 * g + 4 * g + r, 64);
                const float inv = 1.f / lr_r;
                #pragma unroll
                for (int df = 0; df < 4; ++df)
                    out[(size_t)(b * Nn + og) * Cc + h * HD + 16 * df + l16] =
                        f2bf(oacc[u][df][r] * inv);
            }
        }
}

extern "C" void kernel_launch(void* const* d_in, const int* in_sizes, int n_in,
                              void* d_out, int out_size, void* d_ws, size_t ws_size,
                              hipStream_t stream) {
    const float* x      = (const float*)d_in[0];
    const float* w_qkv  = (const float*)d_in[1];
    const float* b_qkv  = (const float*)d_in[2];
    const float* scale  = (const float*)d_in[3];
    const float* w_proj = (const float*)d_in[4];
    const float* b_proj = (const float*)d_in[5];
    float* out = (float*)d_out;

    const int B = 32, N = 577, C = 768, H = 12;
    const int M  = B * N;     // 18464
    const int C3 = 3 * C;     // 2304
    const int MB2 = (M + 255) / 256;   // 73

    short* qkvb   = (short*)d_ws;
    short* attn_o = qkvb + (size_t)M * C3;
    short* xb     = attn_o + (size_t)M * C;
    short* wqkvT  = xb + (size_t)M * C;
    short* wprojT = wqkvT + (size_t)C3 * C;
    short* vT     = wprojT + (size_t)C * C;   // B*H x 64 x 640

    dim3 blk(256);
    const long n4 = (long)M * C / 4;
    convert_bf16<<<dim3((n4 + 255) / 256), blk, 0, stream>>>(x, xb, n4);
    transpose_bf16<<<dim3(C3 / 32, C / 32), blk, 0, stream>>>(w_qkv, wqkvT, C, C3);
    transpose_bf16<<<dim3(C / 32, C / 32), blk, 0, stream>>>(w_proj, wprojT, C, C);

    gemm_bf16<short><<<dim3(MB2 * (C3 / 128)), blk, 0, stream>>>(
        xb, wqkvT, b_qkv, qkvb, M, C3, C, C3 / 128);

    transpose_v<<<dim3(B * H, 20), blk, 0, stream>>>(qkvb, vT);

    flash_attn<<<dim3(((N + 127) / 128) * H * B), blk, 0, stream>>>(qkvb, vT, scale, attn_o);

    gemm_bf16<float><<<dim3(MB2 * (C / 128)), blk, 0, stream>>>(
        attn_o, wprojT, b_proj, out, M, C, C, C / 128);
}

// Round 17
// 245.971 us; speedup vs baseline: 1.0690x; 1.0042x over previous
//
#include <hip/hip_runtime.h>
#include <math.h>

#define HD 64
#define KVBLK 64
#define LP 72

typedef __attribute__((ext_vector_type(8))) short short8;
typedef __attribute__((ext_vector_type(4))) short short4v;
typedef __attribute__((ext_vector_type(4))) float f32x4;

__device__ __forceinline__ short f2bf(float f) {
    union { float f; unsigned u; } in;
    in.f = f;
    unsigned r = (in.u + 0x7fff + ((in.u >> 16) & 1)) >> 16;  // RNE
    return (short)r;
}

// ---------------- fp32 -> bf16 convert ----------------
__global__ __launch_bounds__(256) void convert_bf16(const float* __restrict__ in,
                                                    short* __restrict__ out, long n4) {
    long i = blockIdx.x * 256L + threadIdx.x;
    if (i >= n4) return;
    float4 v = reinterpret_cast<const float4*>(in)[i];
    short4v o;
    o[0] = f2bf(v.x); o[1] = f2bf(v.y); o[2] = f2bf(v.z); o[3] = f2bf(v.w);
    reinterpret_cast<short4v*>(out)[i] = o;
}

// ---- fused weight transpose: w_qkv [768][2304] + w_proj [768][768] -> [N][K] bf16 ----
__global__ __launch_bounds__(256) void transpose_w(const float* __restrict__ wqkv,
                                                   const float* __restrict__ wproj,
                                                   short* __restrict__ outq,
                                                   short* __restrict__ outp) {
    __shared__ float tile[32][33];
    const int bx = blockIdx.x;
    const bool isq = bx < 72;
    const float* in = isq ? wqkv : wproj;
    short* out = isq ? outq : outp;
    const int N = isq ? 2304 : 768;
    const int n0 = (isq ? bx : bx - 72) * 32, k0 = blockIdx.y * 32;
    const int tx = threadIdx.x & 31, ty = threadIdx.x >> 5;
    #pragma unroll
    for (int i = ty; i < 32; i += 8)
        tile[i][tx] = in[(size_t)(k0 + i) * N + n0 + tx];
    __syncthreads();
    #pragma unroll
    for (int i = ty; i < 32; i += 8)
        out[(size_t)(n0 + i) * 768 + k0 + tx] = f2bf(tile[tx][i]);
}

// ------- V pre-transpose: qkv V-part [b][key][h][d] -> vT[(b*H+h)][d][key640] -------
__global__ __launch_bounds__(256) void transpose_v(const short* __restrict__ qkvb,
                                                   short* __restrict__ vT) {
    constexpr int Nn = 577, C3 = 2304, NH = 12, NKP = 640;
    const int bh = blockIdx.x;
    const int kt = blockIdx.y;
    const int b = bh / NH, h = bh % NH;
    const int tid = threadIdx.x;
    __shared__ short tile[64][33];

    const int tk = tid >> 3;
    const int key = kt * 32 + tk;
    const int d0 = (tid & 7) * 8;
    short8 v = {0, 0, 0, 0, 0, 0, 0, 0};
    if (key < Nn)
        v = *reinterpret_cast<const short8*>(
            qkvb + (size_t)(b * Nn + key) * C3 + 1536 + h * 64 + d0);
    #pragma unroll
    for (int i = 0; i < 8; ++i) tile[d0 + i][tk] = v[i];
    __syncthreads();

    const int d = tid >> 2;
    const int kb = (tid & 3) * 8;
    short8 o;
    #pragma unroll
    for (int i = 0; i < 8; ++i) o[i] = tile[d][kb + i];
    *reinterpret_cast<short8*>(vT + (size_t)(bh * 64 + d) * NKP + kt * 32 + kb) = o;
}

// ------- bf16 MFMA GEMM: 256x128 tile, 8x4 wave blocking, BK=32, 2-buf (r14) -------
template <typename OutT>
__global__ __launch_bounds__(256, 2) void gemm_bf16(const short* __restrict__ A,
                                                    const short* __restrict__ Bt,
                                                    const float* __restrict__ bias,
                                                    OutT* __restrict__ C,
                                                    int M, int N, int K, int nbn) {
    __shared__ short As[2][128 * 64];   // 256 rows packed in pairs
    __shared__ short Bs[2][64 * 64];    // 128 rows packed in pairs
    const int tid = threadIdx.x;
    const int w = tid >> 6, lane = tid & 63;
    const int g = lane >> 4, l16 = lane & 15;

    const int nwg = gridDim.x;
    const int q = nwg >> 3, r = nwg & 7;
    const int xcd = blockIdx.x & 7, loc = blockIdx.x >> 3;
    const int wgid = (xcd < r ? xcd * (q + 1) : r * (q + 1) + (xcd - r) * q) + loc;
    const int bm = wgid / nbn, bn = wgid % nbn;
    const int m0 = bm * 256, n0 = bn * 128;
    const int wm = (w >> 1) * 128, wn = (w & 1) * 64;

    f32x4 acc[8][4] = {};
    const int NT = K >> 5;   // BK=32

    auto stage = [&](int buf, int k0) {
        #pragma unroll
        for (int j = 0; j < 4; ++j) {
            const int o = j * 4096 + tid * 16;
            const int R = o >> 7;
            const int sl = ((o >> 4) & 7) ^ (R & 7);
            const int rr = 2 * R + (sl >> 2);
            const int cblk = sl & 3;
            long arow = m0 + rr; if (arow > M - 1) arow = M - 1;
            const short* ga = A + arow * K + k0 + cblk * 8;
            __builtin_amdgcn_global_load_lds(
                (const __attribute__((address_space(1))) unsigned*)ga,
                (__attribute__((address_space(3))) unsigned*)((char*)&As[buf][0] + o),
                16, 0, 0);
        }
        #pragma unroll
        for (int j = 0; j < 2; ++j) {
            const int o = j * 4096 + tid * 16;
            const int R = o >> 7;
            const int sl = ((o >> 4) & 7) ^ (R & 7);
            const int rr = 2 * R + (sl >> 2);
            const int cblk = sl & 3;
            const short* gb = Bt + (size_t)(n0 + rr) * K + k0 + cblk * 8;
            __builtin_amdgcn_global_load_lds(
                (const __attribute__((address_space(1))) unsigned*)gb,
                (__attribute__((address_space(3))) unsigned*)((char*)&Bs[buf][0] + o),
                16, 0, 0);
        }
    };

    stage(0, 0);
    __syncthreads();

    for (int kt = 0; kt < NT; ++kt) {
        const int cur = kt & 1;
        if (kt + 1 < NT) stage(cur ^ 1, (kt + 1) * 32);

        short8 af[8], bfr[4];
        #pragma unroll
        for (int mi = 0; mi < 8; ++mi) {
            const int ra = wm + mi * 16 + l16;
            const int Ra = ra >> 1;
            const int sla = (4 * (ra & 1) + g) ^ (Ra & 7);
            af[mi] = *reinterpret_cast<const short8*>(&As[cur][Ra * 64 + sla * 8]);
        }
        #pragma unroll
        for (int ni = 0; ni < 4; ++ni) {
            const int rb = wn + ni * 16 + l16;
            const int Rb = rb >> 1;
            const int slb = (4 * (rb & 1) + g) ^ (Rb & 7);
            bfr[ni] = *reinterpret_cast<const short8*>(&Bs[cur][Rb * 64 + slb * 8]);
        }
        __builtin_amdgcn_s_setprio(1);
        #pragma unroll
        for (int mi = 0; mi < 8; ++mi)
            #pragma unroll
            for (int ni = 0; ni < 4; ++ni)
                acc[mi][ni] = __builtin_amdgcn_mfma_f32_16x16x32_bf16(
                    af[mi], bfr[ni], acc[mi][ni], 0, 0, 0);
        __builtin_amdgcn_s_setprio(0);
        __syncthreads();
    }

    float bv[4];
    #pragma unroll
    for (int ni = 0; ni < 4; ++ni) bv[ni] = bias[n0 + wn + ni * 16 + l16];
    #pragma unroll
    for (int mi = 0; mi < 8; ++mi) {
        #pragma unroll
        for (int rr = 0; rr < 4; ++rr) {
            const int row = m0 + wm + mi * 16 + g * 4 + rr;
            if (row < M) {
                #pragma unroll
                for (int ni = 0; ni < 4; ++ni) {
                    float val = acc[mi][ni][rr] + bv[ni];
                    if constexpr (__is_same(OutT, float))
                        C[(size_t)row * N + n0 + wn + ni * 16 + l16] = val;
                    else
                        C[(size_t)row * N + n0 + wn + ni * 16 + l16] = f2bf(val);
                }
            }
        }
    }
}

// ------- flash attention: QBLK=128, shared-fragment-hoisted across q-groups -------
__global__ __launch_bounds__(256) void flash_attn(const short* __restrict__ qkvb,
                                                  const short* __restrict__ vT,
                                                  const float* __restrict__ scale,
                                                  short* __restrict__ out) {
    constexpr int Nn = 577, Cc = 768, C3 = 2304, NQB = 5, NH = 12, NT = 10, NKP = 640;
    const int bid = blockIdx.x;
    const int swz = (bid & 7) * 240 + (bid >> 3);   // 1920 blocks, 240 per XCD
    const int q0 = (swz % NQB) * 128;
    const int h  = (swz / NQB) % NH;
    const int b  = swz / (NQB * NH);
    const int qb2 = q0 >> 6;

    const int tid  = threadIdx.x;
    const int w    = tid >> 6;
    const int lane = tid & 63;
    const int g    = lane >> 4;
    const int l16  = lane & 15;

    __shared__ alignas(16) short Ks[2][KVBLK * HD];
    __shared__ alignas(16) short Vts[2][HD * KVBLK];
    __shared__ alignas(16) short Ps[4][2][16][LP];

    const float sl2 = scale[h] * 1.44269504088896f;
    const float thr = 8.0f / sl2;
    const short* base = qkvb + (size_t)b * Nn * C3;
    const short* kglob = base + Cc + h * HD;
    const short* vtb = vT + (size_t)(b * NH + h) * HD * NKP;

    short8 aq[2][2];
    #pragma unroll
    for (int u = 0; u < 2; ++u) {
        const int qrow = q0 + u * 64 + w * 16 + l16;
        const int qr = qrow < Nn ? qrow : Nn - 1;
        const short* qp = base + (size_t)qr * C3 + h * HD;
        aq[u][0] = *reinterpret_cast<const short8*>(qp + 8 * g);
        aq[u][1] = *reinterpret_cast<const short8*>(qp + 32 + 8 * g);
    }

    f32x4 oacc[2][4] = {};
    float mrun[2] = {-INFINITY, -INFINITY}, m2[2] = {-INFINITY, -INFINITY},
          lrun[2] = {0.f, 0.f};

    const int kst_row = lane >> 3;
    const int kst_dblk = (lane & 7) ^ (lane >> 3);

    auto stageK = [&](int bufi, int kv0) {
        #pragma unroll
        for (int t = 0; t < 2; ++t) {
            const int i = 2 * w + t;
            int kr = kv0 + 8 * i + kst_row;
            if (kr > Nn - 1) kr = Nn - 1;
            const short* src = kglob + (size_t)kr * C3 + kst_dblk * 8;
            __builtin_amdgcn_global_load_lds(
                (const __attribute__((address_space(1))) unsigned*)src,
                (__attribute__((address_space(3))) unsigned*)&Ks[bufi][i * 512],
                16, 0, 0);
        }
    };
    auto stageV = [&](int bufi, int kv0) {
        #pragma unroll
        for (int t = 0; t < 2; ++t) {
            const int i = 2 * w + t;
            const int r = 8 * i + kst_row;
            const int kb = (lane & 7) ^ (r & 7);
            const short* src = vtb + (size_t)r * NKP + kv0 + kb * 8;
            __builtin_amdgcn_global_load_lds(
                (const __attribute__((address_space(1))) unsigned*)src,
                (__attribute__((address_space(3))) unsigned*)&Vts[bufi][i * 512],
                16, 0, 0);
        }
    };

    stageK(0, 0);
    stageV(0, 0);
    __syncthreads();

    for (int t = 0; t < NT; ++t) {
        const int cur = t & 1, nxt = cur ^ 1;
        const int kv0 = t * KVBLK;
        const bool more = (t + 1 < NT);
        if (more) { stageK(nxt, kv0 + KVBLK); stageV(nxt, kv0 + KVBLK); }

        // ---- S^T: ak loaded ONCE, shared by both q-groups ----
        f32x4 sacc[2][4] = {};
        __builtin_amdgcn_s_setprio(1);
        #pragma unroll
        for (int f = 0; f < 4; ++f) {
            #pragma unroll
            for (int c = 0; c < 2; ++c) {
                const int slot = (4 * c + g) ^ (l16 & 7);
                short8 ak = *reinterpret_cast<const short8*>(
                    &Ks[cur][(16 * f + l16) * 64 + slot * 8]);
                sacc[0][f] = __builtin_amdgcn_mfma_f32_16x16x32_bf16(
                    ak, aq[0][c], sacc[0][f], 0, 0, 0);
                sacc[1][f] = __builtin_amdgcn_mfma_f32_16x16x32_bf16(
                    ak, aq[1][c], sacc[1][f], 0, 0, 0);
            }
        }
        __builtin_amdgcn_s_setprio(0);

        #pragma unroll
        for (int u = 0; u < 2; ++u) {
            const int ig = q0 + u * 64 + w * 16 + l16;
            float s2[4][4];
            #pragma unroll
            for (int f = 0; f < 4; ++f)
                #pragma unroll
                for (int r = 0; r < 4; ++r)
                    s2[f][r] = sacc[u][f][r];
            if (t == qb2 + u || t == NT - 1) {
                #pragma unroll
                for (int f = 0; f < 4; ++f)
                    #pragma unroll
                    for (int r = 0; r < 4; ++r) {
                        const int jg = kv0 + 16 * f + 4 * g + r;
                        if (jg >= Nn || (jg == ig && ig >= 1)) s2[f][r] = -INFINITY;
                    }
            }

            float mx = s2[0][0];
            #pragma unroll
            for (int f = 0; f < 4; ++f)
                #pragma unroll
                for (int r = 0; r < 4; ++r)
                    if (f + r) mx = fmaxf(mx, s2[f][r]);
            mx = fmaxf(mx, __shfl_xor(mx, 16, 64));
            mx = fmaxf(mx, __shfl_xor(mx, 32, 64));

            if (__any(mx > mrun[u] + thr)) {
                const float mnew = fmaxf(mrun[u], mx);
                const float m2new = mnew * sl2;
                const float fac = __builtin_amdgcn_exp2f(m2[u] - m2new);
                mrun[u] = mnew; m2[u] = m2new;
                lrun[u] *= fac;
                #pragma unroll
                for (int r = 0; r < 4; ++r) {
                    const float fr = __shfl(fac, 16 * g + 4 * g + r, 64);
                    #pragma unroll
                    for (int df = 0; df < 4; ++df) oacc[u][df][r] *= fr;
                }
            }

            float sum = 0.f;
            #pragma unroll
            for (int f = 0; f < 4; ++f)
                #pragma unroll
                for (int r = 0; r < 4; ++r) {
                    float p = __builtin_amdgcn_exp2f(fmaf(s2[f][r], sl2, -m2[u]));
                    s2[f][r] = p;
                    sum += p;
                }
            sum += __shfl_xor(sum, 16, 64);
            sum += __shfl_xor(sum, 32, 64);
            lrun[u] += sum;

            #pragma unroll
            for (int f = 0; f < 4; ++f) {
                unsigned plo, phi;
                asm("v_cvt_pk_bf16_f32 %0, %1, %2" : "=v"(plo) : "v"(s2[f][0]), "v"(s2[f][1]));
                asm("v_cvt_pk_bf16_f32 %0, %1, %2" : "=v"(phi) : "v"(s2[f][2]), "v"(s2[f][3]));
                unsigned* dst = reinterpret_cast<unsigned*>(&Ps[w][u][l16][16 * f + 4 * g]);
                dst[0] = plo; dst[1] = phi;
            }
        }
        asm volatile("s_waitcnt lgkmcnt(0)" ::: "memory");

        // ---- O += P @ V: bv loaded ONCE, shared by both q-groups ----
        __builtin_amdgcn_s_setprio(1);
        #pragma unroll
        for (int c = 0; c < 2; ++c) {
            short8 pa0 = *reinterpret_cast<const short8*>(&Ps[w][0][l16][32 * c + 8 * g]);
            short8 pa1 = *reinterpret_cast<const short8*>(&Ps[w][1][l16][32 * c + 8 * g]);
            const int slot = (4 * c + g) ^ (l16 & 7);
            #pragma unroll
            for (int df = 0; df < 4; ++df) {
                short8 bv = *reinterpret_cast<const short8*>(
                    &Vts[cur][(16 * df + l16) * 64 + slot * 8]);
                oacc[0][df] = __builtin_amdgcn_mfma_f32_16x16x32_bf16(
                    pa0, bv, oacc[0][df], 0, 0, 0);
                oacc[1][df] = __builtin_amdgcn_mfma_f32_16x16x32_bf16(
                    pa1, bv, oacc[1][df], 0, 0, 0);
            }
        }
        __builtin_amdgcn_s_setprio(0);
        __syncthreads();
    }

    #pragma unroll
    for (int u = 0; u < 2; ++u)
        #pragma unroll
        for (int r = 0; r < 4; ++r) {
            const int og = q0 + u * 64 + w * 16 + g * 4 + r;
            if (og < Nn) {
                const float lr_r = __shfl(lrun[u], 16 * g + 4 * g + r, 64);
                const float inv = 1.f / lr_r;
                #pragma unroll
                for (int df = 0; df < 4; ++df)
                    out[(size_t)(b * Nn + og) * Cc + h * HD + 16 * df + l16] =
                        f2bf(oacc[u][df][r] * inv);
            }
        }
}

extern "C" void kernel_launch(void* const* d_in, const int* in_sizes, int n_in,
                              void* d_out, int out_size, void* d_ws, size_t ws_size,
                              hipStream_t stream) {
    const float* x      = (const float*)d_in[0];
    const float* w_qkv  = (const float*)d_in[1];
    const float* b_qkv  = (const float*)d_in[2];
    const float* scale  = (const float*)d_in[3];
    const float* w_proj = (const float*)d_in[4];
    const float* b_proj = (const float*)d_in[5];
    float* out = (float*)d_out;

    const int B = 32, N = 577, C = 768, H = 12;
    const int M  = B * N;     // 18464
    const int C3 = 3 * C;     // 2304
    const int MB2 = (M + 255) / 256;   // 73

    short* qkvb   = (short*)d_ws;
    short* attn_o = qkvb + (size_t)M * C3;
    short* xb     = attn_o + (size_t)M * C;
    short* wqkvT  = xb + (size_t)M * C;
    short* wprojT = wqkvT + (size_t)C3 * C;
    short* vT     = wprojT + (size_t)C * C;   // B*H x 64 x 640

    dim3 blk(256);
    const long n4 = (long)M * C / 4;
    convert_bf16<<<dim3((n4 + 255) / 256), blk, 0, stream>>>(x, xb, n4);
    transpose_w<<<dim3(96, 24), blk, 0, stream>>>(w_qkv, w_proj, wqkvT, wprojT);

    gemm_bf16<short><<<dim3(MB2 * (C3 / 128)), blk, 0, stream>>>(
        xb, wqkvT, b_qkv, qkvb, M, C3, C, C3 / 128);

    transpose_v<<<dim3(B * H, 20), blk, 0, stream>>>(qkvb, vT);

    flash_attn<<<dim3(((N + 127) / 128) * H * B), blk, 0, stream>>>(qkvb, vT, scale, attn_o);

    gemm_bf16<float><<<dim3(MB2 * (C / 128)), blk, 0, stream>>>(
        attn_o, wprojT, b_proj, out, M, C, C, C / 128);
}

// Round 18
// 244.024 us; speedup vs baseline: 1.0776x; 1.0080x over previous
//
#include <hip/hip_runtime.h>
#include <math.h>

#define HD 64
#define KVBLK 64
#define LP 72

typedef __attribute__((ext_vector_type(8))) short short8;
typedef __attribute__((ext_vector_type(4))) short short4v;
typedef __attribute__((ext_vector_type(4))) float f32x4;

__device__ __forceinline__ short f2bf(float f) {
    union { float f; unsigned u; } in;
    in.f = f;
    unsigned r = (in.u + 0x7fff + ((in.u >> 16) & 1)) >> 16;  // RNE
    return (short)r;
}

// ---- fused prologue: x fp32->bf16 convert  +  weight transpose (both weights) ----
// blocks [0, NCONV): convert x; blocks [NCONV, NCONV+2304): transpose w_qkv/w_proj.
__global__ __launch_bounds__(256) void prep(const float* __restrict__ x,
                                            short* __restrict__ xb,
                                            const float* __restrict__ wqkv,
                                            const float* __restrict__ wproj,
                                            short* __restrict__ outq,
                                            short* __restrict__ outp,
                                            long n4, int nconv) {
    const int bid = blockIdx.x;
    if (bid < nconv) {
        long i = bid * 256L + threadIdx.x;
        if (i >= n4) return;
        float4 v = reinterpret_cast<const float4*>(x)[i];
        short4v o;
        o[0] = f2bf(v.x); o[1] = f2bf(v.y); o[2] = f2bf(v.z); o[3] = f2bf(v.w);
        reinterpret_cast<short4v*>(xb)[i] = o;
        return;
    }
    __shared__ float tile[32][33];
    const int rem = bid - nconv;
    const int bx = rem % 96, ky = rem / 96;
    const bool isq = bx < 72;
    const float* in = isq ? wqkv : wproj;
    short* out = isq ? outq : outp;
    const int N = isq ? 2304 : 768;
    const int n0 = (isq ? bx : bx - 72) * 32, k0 = ky * 32;
    const int tx = threadIdx.x & 31, ty = threadIdx.x >> 5;
    #pragma unroll
    for (int i = ty; i < 32; i += 8)
        tile[i][tx] = in[(size_t)(k0 + i) * N + n0 + tx];
    __syncthreads();
    #pragma unroll
    for (int i = ty; i < 32; i += 8)
        out[(size_t)(n0 + i) * 768 + k0 + tx] = f2bf(tile[tx][i]);
}

// ------- V pre-transpose: qkv V-part [b][key][h][d] -> vT[(b*H+h)][d][key640] -------
__global__ __launch_bounds__(256) void transpose_v(const short* __restrict__ qkvb,
                                                   short* __restrict__ vT) {
    constexpr int Nn = 577, C3 = 2304, NH = 12, NKP = 640;
    const int bh = blockIdx.x;
    const int kt = blockIdx.y;
    const int b = bh / NH, h = bh % NH;
    const int tid = threadIdx.x;
    __shared__ short tile[64][33];

    const int tk = tid >> 3;
    const int key = kt * 32 + tk;
    const int d0 = (tid & 7) * 8;
    short8 v = {0, 0, 0, 0, 0, 0, 0, 0};
    if (key < Nn)
        v = *reinterpret_cast<const short8*>(
            qkvb + (size_t)(b * Nn + key) * C3 + 1536 + h * 64 + d0);
    #pragma unroll
    for (int i = 0; i < 8; ++i) tile[d0 + i][tk] = v[i];
    __syncthreads();

    const int d = tid >> 2;
    const int kb = (tid & 3) * 8;
    short8 o;
    #pragma unroll
    for (int i = 0; i < 8; ++i) o[i] = tile[d][kb + i];
    *reinterpret_cast<short8*>(vT + (size_t)(bh * 64 + d) * NKP + kt * 32 + kb) = o;
}

// ------- bf16 MFMA GEMM: 256x128 tile, 8x4 wave blocking, BK=32, 2-buf (r14) -------
template <typename OutT>
__global__ __launch_bounds__(256, 2) void gemm_bf16(const short* __restrict__ A,
                                                    const short* __restrict__ Bt,
                                                    const float* __restrict__ bias,
                                                    OutT* __restrict__ C,
                                                    int M, int N, int K, int nbn) {
    __shared__ short As[2][128 * 64];   // 256 rows packed in pairs
    __shared__ short Bs[2][64 * 64];    // 128 rows packed in pairs
    const int tid = threadIdx.x;
    const int w = tid >> 6, lane = tid & 63;
    const int g = lane >> 4, l16 = lane & 15;

    const int nwg = gridDim.x;
    const int q = nwg >> 3, r = nwg & 7;
    const int xcd = blockIdx.x & 7, loc = blockIdx.x >> 3;
    const int wgid = (xcd < r ? xcd * (q + 1) : r * (q + 1) + (xcd - r) * q) + loc;
    const int bm = wgid / nbn, bn = wgid % nbn;
    const int m0 = bm * 256, n0 = bn * 128;
    const int wm = (w >> 1) * 128, wn = (w & 1) * 64;

    f32x4 acc[8][4] = {};
    const int NT = K >> 5;   // BK=32

    auto stage = [&](int buf, int k0) {
        #pragma unroll
        for (int j = 0; j < 4; ++j) {
            const int o = j * 4096 + tid * 16;
            const int R = o >> 7;
            const int sl = ((o >> 4) & 7) ^ (R & 7);
            const int rr = 2 * R + (sl >> 2);
            const int cblk = sl & 3;
            long arow = m0 + rr; if (arow > M - 1) arow = M - 1;
            const short* ga = A + arow * K + k0 + cblk * 8;
            __builtin_amdgcn_global_load_lds(
                (const __attribute__((address_space(1))) unsigned*)ga,
                (__attribute__((address_space(3))) unsigned*)((char*)&As[buf][0] + o),
                16, 0, 0);
        }
        #pragma unroll
        for (int j = 0; j < 2; ++j) {
            const int o = j * 4096 + tid * 16;
            const int R = o >> 7;
            const int sl = ((o >> 4) & 7) ^ (R & 7);
            const int rr = 2 * R + (sl >> 2);
            const int cblk = sl & 3;
            const short* gb = Bt + (size_t)(n0 + rr) * K + k0 + cblk * 8;
            __builtin_amdgcn_global_load_lds(
                (const __attribute__((address_space(1))) unsigned*)gb,
                (__attribute__((address_space(3))) unsigned*)((char*)&Bs[buf][0] + o),
                16, 0, 0);
        }
    };

    stage(0, 0);
    __syncthreads();

    for (int kt = 0; kt < NT; ++kt) {
        const int cur = kt & 1;
        if (kt + 1 < NT) stage(cur ^ 1, (kt + 1) * 32);

        short8 af[8], bfr[4];
        #pragma unroll
        for (int mi = 0; mi < 8; ++mi) {
            const int ra = wm + mi * 16 + l16;
            const int Ra = ra >> 1;
            const int sla = (4 * (ra & 1) + g) ^ (Ra & 7);
            af[mi] = *reinterpret_cast<const short8*>(&As[cur][Ra * 64 + sla * 8]);
        }
        #pragma unroll
        for (int ni = 0; ni < 4; ++ni) {
            const int rb = wn + ni * 16 + l16;
            const int Rb = rb >> 1;
            const int slb = (4 * (rb & 1) + g) ^ (Rb & 7);
            bfr[ni] = *reinterpret_cast<const short8*>(&Bs[cur][Rb * 64 + slb * 8]);
        }
        __builtin_amdgcn_s_setprio(1);
        #pragma unroll
        for (int mi = 0; mi < 8; ++mi)
            #pragma unroll
            for (int ni = 0; ni < 4; ++ni)
                acc[mi][ni] = __builtin_amdgcn_mfma_f32_16x16x32_bf16(
                    af[mi], bfr[ni], acc[mi][ni], 0, 0, 0);
        __builtin_amdgcn_s_setprio(0);
        __syncthreads();
    }

    float bv[4];
    #pragma unroll
    for (int ni = 0; ni < 4; ++ni) bv[ni] = bias[n0 + wn + ni * 16 + l16];
    #pragma unroll
    for (int mi = 0; mi < 8; ++mi) {
        #pragma unroll
        for (int rr = 0; rr < 4; ++rr) {
            const int row = m0 + wm + mi * 16 + g * 4 + rr;
            if (row < M) {
                #pragma unroll
                for (int ni = 0; ni < 4; ++ni) {
                    float val = acc[mi][ni][rr] + bv[ni];
                    if constexpr (__is_same(OutT, float))
                        C[(size_t)row * N + n0 + wn + ni * 16 + l16] = val;
                    else
                        C[(size_t)row * N + n0 + wn + ni * 16 + l16] = f2bf(val);
                }
            }
        }
    }
}

// ------- flash attention: QBLK=128, hoisted fragments, max3 tree softmax -------
__global__ __launch_bounds__(256) void flash_attn(const short* __restrict__ qkvb,
                                                  const short* __restrict__ vT,
                                                  const float* __restrict__ scale,
                                                  short* __restrict__ out) {
    constexpr int Nn = 577, Cc = 768, C3 = 2304, NQB = 5, NH = 12, NT = 10, NKP = 640;
    const int bid = blockIdx.x;
    const int swz = (bid & 7) * 240 + (bid >> 3);   // 1920 blocks, 240 per XCD
    const int q0 = (swz % NQB) * 128;
    const int h  = (swz / NQB) % NH;
    const int b  = swz / (NQB * NH);
    const int qb2 = q0 >> 6;

    const int tid  = threadIdx.x;
    const int w    = tid >> 6;
    const int lane = tid & 63;
    const int g    = lane >> 4;
    const int l16  = lane & 15;

    __shared__ alignas(16) short Ks[2][KVBLK * HD];
    __shared__ alignas(16) short Vts[2][HD * KVBLK];
    __shared__ alignas(16) short Ps[4][2][16][LP];

    const float sl2 = scale[h] * 1.44269504088896f;
    const float thr = 8.0f / sl2;
    const short* base = qkvb + (size_t)b * Nn * C3;
    const short* kglob = base + Cc + h * HD;
    const short* vtb = vT + (size_t)(b * NH + h) * HD * NKP;

    short8 aq[2][2];
    #pragma unroll
    for (int u = 0; u < 2; ++u) {
        const int qrow = q0 + u * 64 + w * 16 + l16;
        const int qr = qrow < Nn ? qrow : Nn - 1;
        const short* qp = base + (size_t)qr * C3 + h * HD;
        aq[u][0] = *reinterpret_cast<const short8*>(qp + 8 * g);
        aq[u][1] = *reinterpret_cast<const short8*>(qp + 32 + 8 * g);
    }

    f32x4 oacc[2][4] = {};
    float mrun[2] = {-INFINITY, -INFINITY}, m2[2] = {-INFINITY, -INFINITY},
          lrun[2] = {0.f, 0.f};

    const int kst_row = lane >> 3;
    const int kst_dblk = (lane & 7) ^ (lane >> 3);

    auto stageK = [&](int bufi, int kv0) {
        #pragma unroll
        for (int t = 0; t < 2; ++t) {
            const int i = 2 * w + t;
            int kr = kv0 + 8 * i + kst_row;
            if (kr > Nn - 1) kr = Nn - 1;
            const short* src = kglob + (size_t)kr * C3 + kst_dblk * 8;
            __builtin_amdgcn_global_load_lds(
                (const __attribute__((address_space(1))) unsigned*)src,
                (__attribute__((address_space(3))) unsigned*)&Ks[bufi][i * 512],
                16, 0, 0);
        }
    };
    auto stageV = [&](int bufi, int kv0) {
        #pragma unroll
        for (int t = 0; t < 2; ++t) {
            const int i = 2 * w + t;
            const int r = 8 * i + kst_row;
            const int kb = (lane & 7) ^ (r & 7);
            const short* src = vtb + (size_t)r * NKP + kv0 + kb * 8;
            __builtin_amdgcn_global_load_lds(
                (const __attribute__((address_space(1))) unsigned*)src,
                (__attribute__((address_space(3))) unsigned*)&Vts[bufi][i * 512],
                16, 0, 0);
        }
    };

    stageK(0, 0);
    stageV(0, 0);
    __syncthreads();

    for (int t = 0; t < NT; ++t) {
        const int cur = t & 1, nxt = cur ^ 1;
        const int kv0 = t * KVBLK;
        const bool more = (t + 1 < NT);
        if (more) { stageK(nxt, kv0 + KVBLK); stageV(nxt, kv0 + KVBLK); }

        // ---- S^T: ak loaded once, shared by both q-groups ----
        f32x4 sacc[2][4] = {};
        __builtin_amdgcn_s_setprio(1);
        #pragma unroll
        for (int f = 0; f < 4; ++f) {
            #pragma unroll
            for (int c = 0; c < 2; ++c) {
                const int slot = (4 * c + g) ^ (l16 & 7);
                short8 ak = *reinterpret_cast<const short8*>(
                    &Ks[cur][(16 * f + l16) * 64 + slot * 8]);
                sacc[0][f] = __builtin_amdgcn_mfma_f32_16x16x32_bf16(
                    ak, aq[0][c], sacc[0][f], 0, 0, 0);
                sacc[1][f] = __builtin_amdgcn_mfma_f32_16x16x32_bf16(
                    ak, aq[1][c], sacc[1][f], 0, 0, 0);
            }
        }
        __builtin_amdgcn_s_setprio(0);

        #pragma unroll
        for (int u = 0; u < 2; ++u) {
            const int ig = q0 + u * 64 + w * 16 + l16;
            float s2[4][4];
            #pragma unroll
            for (int f = 0; f < 4; ++f)
                #pragma unroll
                for (int r = 0; r < 4; ++r)
                    s2[f][r] = sacc[u][f][r];
            if (t == qb2 + u || t == NT - 1) {
                #pragma unroll
                for (int f = 0; f < 4; ++f)
                    #pragma unroll
                    for (int r = 0; r < 4; ++r) {
                        const int jg = kv0 + 16 * f + 4 * g + r;
                        if (jg >= Nn || (jg == ig && ig >= 1)) s2[f][r] = -INFINITY;
                    }
            }

            // max3-tree (depth 3): clang fuses nested fmaxf into v_max3_f32
            const float t0 = fmaxf(fmaxf(s2[0][0], s2[0][1]), s2[0][2]);
            const float t1 = fmaxf(fmaxf(s2[0][3], s2[1][0]), s2[1][1]);
            const float t2 = fmaxf(fmaxf(s2[1][2], s2[1][3]), s2[2][0]);
            const float t3 = fmaxf(fmaxf(s2[2][1], s2[2][2]), s2[2][3]);
            const float t4 = fmaxf(fmaxf(s2[3][0], s2[3][1]), s2[3][2]);
            float mx = fmaxf(fmaxf(fmaxf(t0, t1), t2),
                             fmaxf(fmaxf(t3, t4), s2[3][3]));
            mx = fmaxf(mx, __shfl_xor(mx, 16, 64));
            mx = fmaxf(mx, __shfl_xor(mx, 32, 64));

            if (__any(mx > mrun[u] + thr)) {
                const float mnew = fmaxf(mrun[u], mx);
                const float m2new = mnew * sl2;
                const float fac = __builtin_amdgcn_exp2f(m2[u] - m2new);
                mrun[u] = mnew; m2[u] = m2new;
                lrun[u] *= fac;
                #pragma unroll
                for (int r = 0; r < 4; ++r) {
                    const float fr = __shfl(fac, 16 * g + 4 * g + r, 64);
                    #pragma unroll
                    for (int df = 0; df < 4; ++df) oacc[u][df][r] *= fr;
                }
            }

            float sum = 0.f;
            #pragma unroll
            for (int f = 0; f < 4; ++f)
                #pragma unroll
                for (int r = 0; r < 4; ++r) {
                    float p = __builtin_amdgcn_exp2f(fmaf(s2[f][r], sl2, -m2[u]));
                    s2[f][r] = p;
                    sum += p;
                }
            sum += __shfl_xor(sum, 16, 64);
            sum += __shfl_xor(sum, 32, 64);
            lrun[u] += sum;

            #pragma unroll
            for (int f = 0; f < 4; ++f) {
                unsigned plo, phi;
                asm("v_cvt_pk_bf16_f32 %0, %1, %2" : "=v"(plo) : "v"(s2[f][0]), "v"(s2[f][1]));
                asm("v_cvt_pk_bf16_f32 %0, %1, %2" : "=v"(phi) : "v"(s2[f][2]), "v"(s2[f][3]));
                unsigned* dst = reinterpret_cast<unsigned*>(&Ps[w][u][l16][16 * f + 4 * g]);
                dst[0] = plo; dst[1] = phi;
            }
        }
        asm volatile("s_waitcnt lgkmcnt(0)" ::: "memory");

        // ---- O += P @ V: bv loaded once, shared by both q-groups ----
        __builtin_amdgcn_s_setprio(1);
        #pragma unroll
        for (int c = 0; c < 2; ++c) {
            short8 pa0 = *reinterpret_cast<const short8*>(&Ps[w][0][l16][32 * c + 8 * g]);
            short8 pa1 = *reinterpret_cast<const short8*>(&Ps[w][1][l16][32 * c + 8 * g]);
            const int slot = (4 * c + g) ^ (l16 & 7);
            #pragma unroll
            for (int df = 0; df < 4; ++df) {
                short8 bv = *reinterpret_cast<const short8*>(
                    &Vts[cur][(16 * df + l16) * 64 + slot * 8]);
                oacc[0][df] = __builtin_amdgcn_mfma_f32_16x16x32_bf16(
                    pa0, bv, oacc[0][df], 0, 0, 0);
                oacc[1][df] = __builtin_amdgcn_mfma_f32_16x16x32_bf16(
                    pa1, bv, oacc[1][df], 0, 0, 0);
            }
        }
        __builtin_amdgcn_s_setprio(0);
        __syncthreads();
    }

    #pragma unroll
    for (int u = 0; u < 2; ++u)
        #pragma unroll
        for (int r = 0; r < 4; ++r) {
            const int og = q0 + u * 64 + w * 16 + g * 4 + r;
            if (og < Nn) {
                const float lr_r = __shfl(lrun[u], 16 * g + 4 * g + r, 64);
                const float inv = 1.f / lr_r;
                #pragma unroll
                for (int df = 0; df < 4; ++df)
                    out[(size_t)(b * Nn + og) * Cc + h * HD + 16 * df + l16] =
                        f2bf(oacc[u][df][r] * inv);
            }
        }
}

extern "C" void kernel_launch(void* const* d_in, const int* in_sizes, int n_in,
                              void* d_out, int out_size, void* d_ws, size_t ws_size,
                              hipStream_t stream) {
    const float* x      = (const float*)d_in[0];
    const float* w_qkv  = (const float*)d_in[1];
    const float* b_qkv  = (const float*)d_in[2];
    const float* scale  = (const float*)d_in[3];
    const float* w_proj = (const float*)d_in[4];
    const float* b_proj = (const float*)d_in[5];
    float* out = (float*)d_out;

    const int B = 32, N = 577, C = 768, H = 12;
    const int M  = B * N;     // 18464
    const int C3 = 3 * C;     // 2304
    const int MB2 = (M + 255) / 256;   // 73

    short* qkvb   = (short*)d_ws;
    short* attn_o = qkvb + (size_t)M * C3;
    short* xb     = attn_o + (size_t)M * C;
    short* wqkvT  = xb + (size_t)M * C;
    short* wprojT = wqkvT + (size_t)C3 * C;
    short* vT     = wprojT + (size_t)C * C;   // B*H x 64 x 640

    dim3 blk(256);
    const long n4 = (long)M * C / 4;
    const int nconv = (int)((n4 + 255) / 256);
    prep<<<dim3(nconv + 96 * 24), blk, 0, stream>>>(
        x, xb, w_qkv, w_proj, wqkvT, wprojT, n4, nconv);

    gemm_bf16<short><<<dim3(MB2 * (C3 / 128)), blk, 0, stream>>>(
        xb, wqkvT, b_qkv, qkvb, M, C3, C, C3 / 128);

    transpose_v<<<dim3(B * H, 20), blk, 0, stream>>>(qkvb, vT);

    flash_attn<<<dim3(((N + 127) / 128) * H * B), blk, 0, stream>>>(qkvb, vT, scale, attn_o);

    gemm_bf16<float><<<dim3(MB2 * (C / 128)), blk, 0, stream>>>(
        attn_o, wprojT, b_proj, out, M, C, C, C / 128);
}

// Round 19
// 242.582 us; speedup vs baseline: 1.0840x; 1.0059x over previous
//
#include <hip/hip_runtime.h>
#include <math.h>

#define HD 64
#define KVBLK 64
#define LP 72

typedef __attribute__((ext_vector_type(8))) short short8;
typedef __attribute__((ext_vector_type(4))) short short4v;
typedef __attribute__((ext_vector_type(4))) float f32x4;

__device__ __forceinline__ short f2bf(float f) {
    union { float f; unsigned u; } in;
    in.f = f;
    unsigned r = (in.u + 0x7fff + ((in.u >> 16) & 1)) >> 16;  // RNE
    return (short)r;
}

// ---- fused prologue: x fp32->bf16 convert  +  weight transpose (both weights) ----
__global__ __launch_bounds__(256) void prep(const float* __restrict__ x,
                                            short* __restrict__ xb,
                                            const float* __restrict__ wqkv,
                                            const float* __restrict__ wproj,
                                            short* __restrict__ outq,
                                            short* __restrict__ outp,
                                            long n4, int nconv) {
    const int bid = blockIdx.x;
    if (bid < nconv) {
        long i = bid * 256L + threadIdx.x;
        if (i >= n4) return;
        float4 v = reinterpret_cast<const float4*>(x)[i];
        short4v o;
        o[0] = f2bf(v.x); o[1] = f2bf(v.y); o[2] = f2bf(v.z); o[3] = f2bf(v.w);
        reinterpret_cast<short4v*>(xb)[i] = o;
        return;
    }
    __shared__ float tile[32][33];
    const int rem = bid - nconv;
    const int bx = rem % 96, ky = rem / 96;
    const bool isq = bx < 72;
    const float* in = isq ? wqkv : wproj;
    short* out = isq ? outq : outp;
    const int N = isq ? 2304 : 768;
    const int n0 = (isq ? bx : bx - 72) * 32, k0 = ky * 32;
    const int tx = threadIdx.x & 31, ty = threadIdx.x >> 5;
    #pragma unroll
    for (int i = ty; i < 32; i += 8)
        tile[i][tx] = in[(size_t)(k0 + i) * N + n0 + tx];
    __syncthreads();
    #pragma unroll
    for (int i = ty; i < 32; i += 8)
        out[(size_t)(n0 + i) * 768 + k0 + tx] = f2bf(tile[tx][i]);
}

// ------- V pre-transpose: qkv V-part [b][key][h][d] -> vT[(b*H+h)][d][key640] -------
__global__ __launch_bounds__(256) void transpose_v(const short* __restrict__ qkvb,
                                                   short* __restrict__ vT) {
    constexpr int Nn = 577, C3 = 2304, NH = 12, NKP = 640;
    const int bh = blockIdx.x;
    const int kt = blockIdx.y;
    const int b = bh / NH, h = bh % NH;
    const int tid = threadIdx.x;
    __shared__ short tile[64][33];

    const int tk = tid >> 3;
    const int key = kt * 32 + tk;
    const int d0 = (tid & 7) * 8;
    short8 v = {0, 0, 0, 0, 0, 0, 0, 0};
    if (key < Nn)
        v = *reinterpret_cast<const short8*>(
            qkvb + (size_t)(b * Nn + key) * C3 + 1536 + h * 64 + d0);
    #pragma unroll
    for (int i = 0; i < 8; ++i) tile[d0 + i][tk] = v[i];
    __syncthreads();

    const int d = tid >> 2;
    const int kb = (tid & 3) * 8;
    short8 o;
    #pragma unroll
    for (int i = 0; i < 8; ++i) o[i] = tile[d][kb + i];
    *reinterpret_cast<short8*>(vT + (size_t)(bh * 64 + d) * NKP + kt * 32 + kb) = o;
}

// ------- bf16 MFMA GEMM: 256x128 tile, 8x4 wave blocking, BK=32, 2-buf (r14) -------
template <typename OutT>
__global__ __launch_bounds__(256, 2) void gemm_bf16(const short* __restrict__ A,
                                                    const short* __restrict__ Bt,
                                                    const float* __restrict__ bias,
                                                    OutT* __restrict__ C,
                                                    int M, int N, int K, int nbn) {
    __shared__ short As[2][128 * 64];   // 256 rows packed in pairs
    __shared__ short Bs[2][64 * 64];    // 128 rows packed in pairs
    const int tid = threadIdx.x;
    const int w = tid >> 6, lane = tid & 63;
    const int g = lane >> 4, l16 = lane & 15;

    const int nwg = gridDim.x;
    const int q = nwg >> 3, r = nwg & 7;
    const int xcd = blockIdx.x & 7, loc = blockIdx.x >> 3;
    const int wgid = (xcd < r ? xcd * (q + 1) : r * (q + 1) + (xcd - r) * q) + loc;
    const int bm = wgid / nbn, bn = wgid % nbn;
    const int m0 = bm * 256, n0 = bn * 128;
    const int wm = (w >> 1) * 128, wn = (w & 1) * 64;

    f32x4 acc[8][4] = {};
    const int NT = K >> 5;   // BK=32

    auto stage = [&](int buf, int k0) {
        #pragma unroll
        for (int j = 0; j < 4; ++j) {
            const int o = j * 4096 + tid * 16;
            const int R = o >> 7;
            const int sl = ((o >> 4) & 7) ^ (R & 7);
            const int rr = 2 * R + (sl >> 2);
            const int cblk = sl & 3;
            long arow = m0 + rr; if (arow > M - 1) arow = M - 1;
            const short* ga = A + arow * K + k0 + cblk * 8;
            __builtin_amdgcn_global_load_lds(
                (const __attribute__((address_space(1))) unsigned*)ga,
                (__attribute__((address_space(3))) unsigned*)((char*)&As[buf][0] + o),
                16, 0, 0);
        }
        #pragma unroll
        for (int j = 0; j < 2; ++j) {
            const int o = j * 4096 + tid * 16;
            const int R = o >> 7;
            const int sl = ((o >> 4) & 7) ^ (R & 7);
            const int rr = 2 * R + (sl >> 2);
            const int cblk = sl & 3;
            const short* gb = Bt + (size_t)(n0 + rr) * K + k0 + cblk * 8;
            __builtin_amdgcn_global_load_lds(
                (const __attribute__((address_space(1))) unsigned*)gb,
                (__attribute__((address_space(3))) unsigned*)((char*)&Bs[buf][0] + o),
                16, 0, 0);
        }
    };

    stage(0, 0);
    __syncthreads();

    for (int kt = 0; kt < NT; ++kt) {
        const int cur = kt & 1;
        if (kt + 1 < NT) stage(cur ^ 1, (kt + 1) * 32);

        short8 af[8], bfr[4];
        #pragma unroll
        for (int mi = 0; mi < 8; ++mi) {
            const int ra = wm + mi * 16 + l16;
            const int Ra = ra >> 1;
            const int sla = (4 * (ra & 1) + g) ^ (Ra & 7);
            af[mi] = *reinterpret_cast<const short8*>(&As[cur][Ra * 64 + sla * 8]);
        }
        #pragma unroll
        for (int ni = 0; ni < 4; ++ni) {
            const int rb = wn + ni * 16 + l16;
            const int Rb = rb >> 1;
            const int slb = (4 * (rb & 1) + g) ^ (Rb & 7);
            bfr[ni] = *reinterpret_cast<const short8*>(&Bs[cur][Rb * 64 + slb * 8]);
        }
        __builtin_amdgcn_s_setprio(1);
        #pragma unroll
        for (int mi = 0; mi < 8; ++mi)
            #pragma unroll
            for (int ni = 0; ni < 4; ++ni)
                acc[mi][ni] = __builtin_amdgcn_mfma_f32_16x16x32_bf16(
                    af[mi], bfr[ni], acc[mi][ni], 0, 0, 0);
        __builtin_amdgcn_s_setprio(0);
        __syncthreads();
    }

    float bv[4];
    #pragma unroll
    for (int ni = 0; ni < 4; ++ni) bv[ni] = bias[n0 + wn + ni * 16 + l16];
    #pragma unroll
    for (int mi = 0; mi < 8; ++mi) {
        #pragma unroll
        for (int rr = 0; rr < 4; ++rr) {
            const int row = m0 + wm + mi * 16 + g * 4 + rr;
            if (row < M) {
                #pragma unroll
                for (int ni = 0; ni < 4; ++ni) {
                    float val = acc[mi][ni][rr] + bv[ni];
                    if constexpr (__is_same(OutT, float))
                        C[(size_t)row * N + n0 + wn + ni * 16 + l16] = val;
                    else
                        C[(size_t)row * N + n0 + wn + ni * 16 + l16] = f2bf(val);
                }
            }
        }
    }
}

// ------- flash attention: QBLK=128, hoisted fragments, tail-tile specialization -------
__global__ __launch_bounds__(256) void flash_attn(const short* __restrict__ qkvb,
                                                  const short* __restrict__ vT,
                                                  const float* __restrict__ scale,
                                                  short* __restrict__ out) {
    constexpr int Nn = 577, Cc = 768, C3 = 2304, NQB = 5, NH = 12, NT = 10, NKP = 640;
    const int bid = blockIdx.x;
    const int swz = (bid & 7) * 240 + (bid >> 3);   // 1920 blocks, 240 per XCD
    const int q0 = (swz % NQB) * 128;
    const int h  = (swz / NQB) % NH;
    const int b  = swz / (NQB * NH);
    const int qb2 = q0 >> 6;

    const int tid  = threadIdx.x;
    const int w    = tid >> 6;
    const int lane = tid & 63;
    const int g    = lane >> 4;
    const int l16  = lane & 15;

    __shared__ alignas(16) short Ks[2][KVBLK * HD];
    __shared__ alignas(16) short Vts[2][HD * KVBLK];
    __shared__ alignas(16) short Ps[4][2][16][LP];

    const float sl2 = scale[h] * 1.44269504088896f;
    const float thr = 8.0f / sl2;
    const short* base = qkvb + (size_t)b * Nn * C3;
    const short* kglob = base + Cc + h * HD;
    const short* vtb = vT + (size_t)(b * NH + h) * HD * NKP;

    short8 aq[2][2];
    #pragma unroll
    for (int u = 0; u < 2; ++u) {
        const int qrow = q0 + u * 64 + w * 16 + l16;
        const int qr = qrow < Nn ? qrow : Nn - 1;
        const short* qp = base + (size_t)qr * C3 + h * HD;
        aq[u][0] = *reinterpret_cast<const short8*>(qp + 8 * g);
        aq[u][1] = *reinterpret_cast<const short8*>(qp + 32 + 8 * g);
    }

    f32x4 oacc[2][4] = {};
    float mrun[2] = {-INFINITY, -INFINITY}, m2[2] = {-INFINITY, -INFINITY},
          lrun[2] = {0.f, 0.f};

    const int kst_row = lane >> 3;
    const int kst_dblk = (lane & 7) ^ (lane >> 3);

    auto stageK = [&](int bufi, int kv0) {
        #pragma unroll
        for (int t = 0; t < 2; ++t) {
            const int i = 2 * w + t;
            int kr = kv0 + 8 * i + kst_row;
            if (kr > Nn - 1) kr = Nn - 1;
            const short* src = kglob + (size_t)kr * C3 + kst_dblk * 8;
            __builtin_amdgcn_global_load_lds(
                (const __attribute__((address_space(1))) unsigned*)src,
                (__attribute__((address_space(3))) unsigned*)&Ks[bufi][i * 512],
                16, 0, 0);
        }
    };
    auto stageV = [&](int bufi, int kv0) {
        #pragma unroll
        for (int t = 0; t < 2; ++t) {
            const int i = 2 * w + t;
            const int r = 8 * i + kst_row;
            const int kb = (lane & 7) ^ (r & 7);
            const short* src = vtb + (size_t)r * NKP + kv0 + kb * 8;
            __builtin_amdgcn_global_load_lds(
                (const __attribute__((address_space(1))) unsigned*)src,
                (__attribute__((address_space(3))) unsigned*)&Vts[bufi][i * 512],
                16, 0, 0);
        }
    };

    stageK(0, 0);
    stageV(0, 0);
    __syncthreads();

    for (int t = 0; t < NT; ++t) {
        const int cur = t & 1, nxt = cur ^ 1;
        const int kv0 = t * KVBLK;
        const bool more = (t + 1 < NT);
        const bool tail = (t == NT - 1);   // keys 576-639: only key 576 real
        if (more) { stageK(nxt, kv0 + KVBLK); stageV(nxt, kv0 + KVBLK); }

        // ---- S^T: ak loaded once, shared by both q-groups ----
        // Tail: f>=1 covers keys 592-639, ALL masked (jg>=Nn) -> skip those MFMAs;
        // sacc stays 0 and the mask loop overwrites with -inf (bit-identical).
        f32x4 sacc[2][4] = {};
        __builtin_amdgcn_s_setprio(1);
        #pragma unroll
        for (int f = 0; f < 4; ++f) {
            if (tail && f > 0) break;   // wave-uniform branch
            #pragma unroll
            for (int c = 0; c < 2; ++c) {
                const int slot = (4 * c + g) ^ (l16 & 7);
                short8 ak = *reinterpret_cast<const short8*>(
                    &Ks[cur][(16 * f + l16) * 64 + slot * 8]);
                sacc[0][f] = __builtin_amdgcn_mfma_f32_16x16x32_bf16(
                    ak, aq[0][c], sacc[0][f], 0, 0, 0);
                sacc[1][f] = __builtin_amdgcn_mfma_f32_16x16x32_bf16(
                    ak, aq[1][c], sacc[1][f], 0, 0, 0);
            }
        }
        __builtin_amdgcn_s_setprio(0);

        #pragma unroll
        for (int u = 0; u < 2; ++u) {
            const int ig = q0 + u * 64 + w * 16 + l16;
            float s2[4][4];
            #pragma unroll
            for (int f = 0; f < 4; ++f)
                #pragma unroll
                for (int r = 0; r < 4; ++r)
                    s2[f][r] = sacc[u][f][r];
            if (t == qb2 + u || tail) {
                #pragma unroll
                for (int f = 0; f < 4; ++f)
                    #pragma unroll
                    for (int r = 0; r < 4; ++r) {
                        const int jg = kv0 + 16 * f + 4 * g + r;
                        if (jg >= Nn || (jg == ig && ig >= 1)) s2[f][r] = -INFINITY;
                    }
            }

            // max3-tree (depth 3)
            const float t0 = fmaxf(fmaxf(s2[0][0], s2[0][1]), s2[0][2]);
            const float t1 = fmaxf(fmaxf(s2[0][3], s2[1][0]), s2[1][1]);
            const float t2 = fmaxf(fmaxf(s2[1][2], s2[1][3]), s2[2][0]);
            const float t3 = fmaxf(fmaxf(s2[2][1], s2[2][2]), s2[2][3]);
            const float t4 = fmaxf(fmaxf(s2[3][0], s2[3][1]), s2[3][2]);
            float mx = fmaxf(fmaxf(fmaxf(t0, t1), t2),
                             fmaxf(fmaxf(t3, t4), s2[3][3]));
            mx = fmaxf(mx, __shfl_xor(mx, 16, 64));
            mx = fmaxf(mx, __shfl_xor(mx, 32, 64));

            if (__any(mx > mrun[u] + thr)) {
                const float mnew = fmaxf(mrun[u], mx);
                const float m2new = mnew * sl2;
                const float fac = __builtin_amdgcn_exp2f(m2[u] - m2new);
                mrun[u] = mnew; m2[u] = m2new;
                lrun[u] *= fac;
                #pragma unroll
                for (int r = 0; r < 4; ++r) {
                    const float fr = __shfl(fac, 16 * g + 4 * g + r, 64);
                    #pragma unroll
                    for (int df = 0; df < 4; ++df) oacc[u][df][r] *= fr;
                }
            }

            float sum = 0.f;
            #pragma unroll
            for (int f = 0; f < 4; ++f)
                #pragma unroll
                for (int r = 0; r < 4; ++r) {
                    float p = __builtin_amdgcn_exp2f(fmaf(s2[f][r], sl2, -m2[u]));
                    s2[f][r] = p;
                    sum += p;
                }
            sum += __shfl_xor(sum, 16, 64);
            sum += __shfl_xor(sum, 32, 64);
            lrun[u] += sum;

            #pragma unroll
            for (int f = 0; f < 4; ++f) {
                unsigned plo, phi;
                asm("v_cvt_pk_bf16_f32 %0, %1, %2" : "=v"(plo) : "v"(s2[f][0]), "v"(s2[f][1]));
                asm("v_cvt_pk_bf16_f32 %0, %1, %2" : "=v"(phi) : "v"(s2[f][2]), "v"(s2[f][3]));
                unsigned* dst = reinterpret_cast<unsigned*>(&Ps[w][u][l16][16 * f + 4 * g]);
                dst[0] = plo; dst[1] = phi;
            }
        }
        asm volatile("s_waitcnt lgkmcnt(0)" ::: "memory");

        // ---- O += P @ V: bv loaded once, shared by both q-groups ----
        // Tail: c=1 covers keys 608-639, P identically 0 -> skip (exact zeros).
        __builtin_amdgcn_s_setprio(1);
        #pragma unroll
        for (int c = 0; c < 2; ++c) {
            if (tail && c > 0) break;   // wave-uniform branch
            short8 pa0 = *reinterpret_cast<const short8*>(&Ps[w][0][l16][32 * c + 8 * g]);
            short8 pa1 = *reinterpret_cast<const short8*>(&Ps[w][1][l16][32 * c + 8 * g]);
            const int slot = (4 * c + g) ^ (l16 & 7);
            #pragma unroll
            for (int df = 0; df < 4; ++df) {
                short8 bv = *reinterpret_cast<const short8*>(
                    &Vts[cur][(16 * df + l16) * 64 + slot * 8]);
                oacc[0][df] = __builtin_amdgcn_mfma_f32_16x16x32_bf16(
                    pa0, bv, oacc[0][df], 0, 0, 0);
                oacc[1][df] = __builtin_amdgcn_mfma_f32_16x16x32_bf16(
                    pa1, bv, oacc[1][df], 0, 0, 0);
            }
        }
        __builtin_amdgcn_s_setprio(0);
        __syncthreads();
    }

    #pragma unroll
    for (int u = 0; u < 2; ++u)
        #pragma unroll
        for (int r = 0; r < 4; ++r) {
            const int og = q0 + u * 64 + w * 16 + g * 4 + r;
            if (og < Nn) {
                const float lr_r = __shfl(lrun[u], 16 * g + 4 * g + r, 64);
                const float inv = 1.f / lr_r;
                #pragma unroll
                for (int df = 0; df < 4; ++df)
                    out[(size_t)(b * Nn + og) * Cc + h * HD + 16 * df + l16] =
                        f2bf(oacc[u][df][r] * inv);
            }
        }
}

extern "C" void kernel_launch(void* const* d_in, const int* in_sizes, int n_in,
                              void* d_out, int out_size, void* d_ws, size_t ws_size,
                              hipStream_t stream) {
    const float* x      = (const float*)d_in[0];
    const float* w_qkv  = (const float*)d_in[1];
    const float* b_qkv  = (const float*)d_in[2];
    const float* scale  = (const float*)d_in[3];
    const float* w_proj = (const float*)d_in[4];
    const float* b_proj = (const float*)d_in[5];
    float* out = (float*)d_out;

    const int B = 32, N = 577, C = 768, H = 12;
    const int M  = B * N;     // 18464
    const int C3 = 3 * C;     // 2304
    const int MB2 = (M + 255) / 256;   // 73

    short* qkvb   = (short*)d_ws;
    short* attn_o = qkvb + (size_t)M * C3;
    short* xb     = attn_o + (size_t)M * C;
    short* wqkvT  = xb + (size_t)M * C;
    short* wprojT = wqkvT + (size_t)C3 * C;
    short* vT     = wprojT + (size_t)C * C;   // B*H x 64 x 640

    dim3 blk(256);
    const long n4 = (long)M * C / 4;
    const int nconv = (int)((n4 + 255) / 256);
    prep<<<dim3(nconv + 96 * 24), blk, 0, stream>>>(
        x, xb, w_qkv, w_proj, wqkvT, wprojT, n4, nconv);

    gemm_bf16<short><<<dim3(MB2 * (C3 / 128)), blk, 0, stream>>>(
        xb, wqkvT, b_qkv, qkvb, M, C3, C, C3 / 128);

    transpose_v<<<dim3(B * H, 20), blk, 0, stream>>>(qkvb, vT);

    flash_attn<<<dim3(((N + 127) / 128) * H * B), blk, 0, stream>>>(qkvb, vT, scale, attn_o);

    gemm_bf16<float><<<dim3(MB2 * (C / 128)), blk, 0, stream>>>(
        attn_o, wprojT, b_proj, out, M, C, C, C / 128);
}